// Round 15
// baseline (374.307 us; speedup 1.0000x reference)
//
#include <hip/hip_runtime.h>
#include <hip/hip_bf16.h>

#define EDGE_DIM 64
#define UPD 256

typedef __attribute__((ext_vector_type(8))) short bf16x8;
typedef __attribute__((ext_vector_type(4))) float f32x4;

__device__ __forceinline__ short f2bf(float v) {
    __hip_bfloat16 b = __float2bfloat16(v);
    return *(short*)&b;
}
__device__ __forceinline__ float bf2f(short s) {
    __hip_bfloat16 b = *(__hip_bfloat16*)&s;
    return __bfloat162float(b);
}

// Truncation hi/lo split (cheap, ~5 VALU ops).
__device__ __forceinline__ void split_trunc(float v, short& hi, short& lo) {
    unsigned u = __float_as_uint(v);
    unsigned hu = u & 0xFFFF0000u;
    hi = (short)(hu >> 16);
    float rem = v - __uint_as_float(hu);
    lo = (short)(__float_as_uint(rem) >> 16);
}

// ---------------------------------------------------------------------------
// Workspace zeroing: h (float4-wide) + count, one launch.
// ---------------------------------------------------------------------------
__global__ __launch_bounds__(256) void zero_ws_kernel(
    float4* __restrict__ h4, long long n4, int* __restrict__ count, int nn) {
    const long long t = (long long)blockIdx.x * blockDim.x + threadIdx.x;
    const long long stride = (long long)gridDim.x * blockDim.x;
    const float4 z = {0.f, 0.f, 0.f, 0.f};
    for (long long i = t; i < n4; i += stride) h4[i] = z;
    for (long long i = t; i < nn; i += stride) count[i] = 0;
}

// ---------------------------------------------------------------------------
// Per-block idx-dtype detection (deterministic across blocks).
// ---------------------------------------------------------------------------
__device__ __forceinline__ int detect_use64_block(const void* idx_v,
                                                  int n_edge, int nn,
                                                  int* bad_s) {
    if (threadIdx.x == 0) *bad_s = 0;
    __syncthreads();
    const long long* p = (const long long*)idx_v;
    int i = threadIdx.x;
    if (i < 256 && i < n_edge) {
        long long v = p[i];
        if (v < 0 || v >= (long long)nn) *bad_s = 1;  // benign race
    }
    __syncthreads();
    return !(*bad_s);
}

// ---------------------------------------------------------------------------
// Counting sort phase A: per-node histogram (vectorized idx loads).
// ---------------------------------------------------------------------------
__global__ __launch_bounds__(256) void count_kernel(
    const void* __restrict__ idx_v, int n_edge, int nn,
    int* __restrict__ count) {
    __shared__ int bad_s;
    const int use64 = detect_use64_block(idx_v, n_edge, nn, &bad_s);
    const int t = blockIdx.x * blockDim.x + threadIdx.x;
    const int nt = gridDim.x * blockDim.x;
    const int n4 = n_edge >> 2;
    if (use64) {
        const longlong2* p2 = (const longlong2*)idx_v;
        for (int i = t; i < n4; i += nt) {
            longlong2 a = p2[i * 2], b = p2[i * 2 + 1];
            atomicAdd(&count[(int)a.x], 1);
            atomicAdd(&count[(int)a.y], 1);
            atomicAdd(&count[(int)b.x], 1);
            atomicAdd(&count[(int)b.y], 1);
        }
        const long long* p = (const long long*)idx_v;
        for (int e = n4 * 4 + t; e < n_edge; e += nt)
            atomicAdd(&count[(int)p[e]], 1);
    } else {
        const int4* p4 = (const int4*)idx_v;
        for (int i = t; i < n4; i += nt) {
            int4 v = p4[i];
            atomicAdd(&count[v.x], 1);
            atomicAdd(&count[v.y], 1);
            atomicAdd(&count[v.z], 1);
            atomicAdd(&count[v.w], 1);
        }
        const int* p = (const int*)idx_v;
        for (int e = n4 * 4 + t; e < n_edge; e += nt)
            atomicAdd(&count[p[e]], 1);
    }
}

// ---------------------------------------------------------------------------
// Exclusive scan over count[nn] -> base[nn+1]  (3 kernels).
// ---------------------------------------------------------------------------
__global__ __launch_bounds__(256) void scan_a(const int* __restrict__ count,
                                              int* __restrict__ base,
                                              int* __restrict__ partial,
                                              int nn) {
    __shared__ int s[256];
    const int tid = threadIdx.x;
    const int i0 = blockIdx.x * 1024 + tid * 4;
    int c[4], tsum = 0;
#pragma unroll
    for (int j = 0; j < 4; ++j) {
        c[j] = (i0 + j < nn) ? count[i0 + j] : 0;
        tsum += c[j];
    }
    s[tid] = tsum;
    __syncthreads();
    for (int off = 1; off < 256; off <<= 1) {
        int v = (tid >= off) ? s[tid - off] : 0;
        __syncthreads();
        s[tid] += v;
        __syncthreads();
    }
    int run = s[tid] - tsum;
    if (tid == 255) partial[blockIdx.x] = s[255];
#pragma unroll
    for (int j = 0; j < 4; ++j) {
        if (i0 + j < nn) base[i0 + j] = run;
        run += c[j];
    }
}

__global__ __launch_bounds__(256) void scan_b(int* __restrict__ partial,
                                              int nblk) {
    __shared__ int s[256];
    const int tid = threadIdx.x;
    int v = (tid < nblk) ? partial[tid] : 0;
    s[tid] = v;
    __syncthreads();
    for (int off = 1; off < 256; off <<= 1) {
        int u = (tid >= off) ? s[tid - off] : 0;
        __syncthreads();
        s[tid] += u;
        __syncthreads();
    }
    if (tid < nblk) partial[tid] = s[tid] - v;
}

__global__ __launch_bounds__(256) void scan_c(int* __restrict__ base,
                                              int* __restrict__ cursor,
                                              const int* __restrict__ partial,
                                              int nn, int n_edge) {
    const int tid = threadIdx.x;
    const int b = blockIdx.x;
    const int add = partial[b];
    const int i0 = b * 1024 + tid * 4;
#pragma unroll
    for (int j = 0; j < 4; ++j) {
        int i = i0 + j;
        if (i < nn) {
            int v = base[i] + add;
            base[i] = v;
            cursor[i] = v;
        }
    }
    if (b == 0 && tid == 0) base[nn] = n_edge;
}

// ---------------------------------------------------------------------------
// Phase B: scatter (edge,node) pairs into node-sorted slot order (int2).
// ---------------------------------------------------------------------------
__global__ __launch_bounds__(256) void fill_order_kernel(
    const void* __restrict__ idx_v, int n_edge, int nn,
    int* __restrict__ cursor, int2* __restrict__ ordnode) {
    __shared__ int bad_s;
    const int use64 = detect_use64_block(idx_v, n_edge, nn, &bad_s);
    const int t = blockIdx.x * blockDim.x + threadIdx.x;
    const int nt = gridDim.x * blockDim.x;
    const int n4 = n_edge >> 2;
    if (use64) {
        const longlong2* p2 = (const longlong2*)idx_v;
        for (int i = t; i < n4; i += nt) {
            longlong2 a = p2[i * 2], b = p2[i * 2 + 1];
            int e0 = i * 4;
            int nd;
            nd = (int)a.x;
            ordnode[atomicAdd(&cursor[nd], 1)] = make_int2(e0 + 0, nd);
            nd = (int)a.y;
            ordnode[atomicAdd(&cursor[nd], 1)] = make_int2(e0 + 1, nd);
            nd = (int)b.x;
            ordnode[atomicAdd(&cursor[nd], 1)] = make_int2(e0 + 2, nd);
            nd = (int)b.y;
            ordnode[atomicAdd(&cursor[nd], 1)] = make_int2(e0 + 3, nd);
        }
        const long long* p = (const long long*)idx_v;
        for (int e = n4 * 4 + t; e < n_edge; e += nt) {
            int nd = (int)p[e];
            ordnode[atomicAdd(&cursor[nd], 1)] = make_int2(e, nd);
        }
    } else {
        const int4* p4 = (const int4*)idx_v;
        for (int i = t; i < n4; i += nt) {
            int4 v = p4[i];
            int e0 = i * 4;
            ordnode[atomicAdd(&cursor[v.x], 1)] = make_int2(e0 + 0, v.x);
            ordnode[atomicAdd(&cursor[v.y], 1)] = make_int2(e0 + 1, v.y);
            ordnode[atomicAdd(&cursor[v.z], 1)] = make_int2(e0 + 2, v.z);
            ordnode[atomicAdd(&cursor[v.w], 1)] = make_int2(e0 + 3, v.w);
        }
        const int* p = (const int*)idx_v;
        for (int e = n4 * 4 + t; e < n_edge; e += nt) {
            int nd = p[e];
            ordnode[atomicAdd(&cursor[nd], 1)] = make_int2(e, nd);
        }
    }
}

// ---------------------------------------------------------------------------
// Phase C: all-vector-path segmented sum (R12 lean form, 28 VGPR, max occ).
// ---------------------------------------------------------------------------
__global__ __launch_bounds__(256) void segsum2_kernel(
    const float* __restrict__ x, const float* __restrict__ rbf,
    const int2* __restrict__ ordnode, const float* __restrict__ Wrbf,
    float* __restrict__ h, int n_edge) {
    const int lane = threadIdx.x & 63;
    float wreg[16];
#pragma unroll
    for (int q = 0; q < 16; ++q) wreg[q] = Wrbf[q * EDGE_DIM + lane];

    const int wid = threadIdx.x >> 6;
    const int nchunks = (n_edge + 63) >> 6;
    const int stride = gridDim.x * 4;

    for (int c = blockIdx.x * 4 + wid; c < nchunks; c += stride) {
        const int s0 = c * 64;
        int slot = s0 + lane;
        if (slot >= n_edge) slot = n_edge - 1;  // clamp (tail only)
        const int2 on = ordnode[slot];          // one 8B per-lane load
        const int ev = on.x;
        const int ndv = on.y;

        float acc = 0.f;
        int cur = -1;
#pragma unroll
        for (int g = 0; g < 4; ++g) {
            const int j0 = g * 16;
            int e[16];
            float xv[16], rv[16];
#pragma unroll
            for (int j = 0; j < 16; ++j) {
                e[j] = __builtin_amdgcn_readlane(ev, j0 + j);  // SGPR
                xv[j] = x[(size_t)e[j] * EDGE_DIM + lane];
                rv[j] = rbf[(size_t)e[j] * 16 + (lane & 15)];
            }
#pragma unroll
            for (int j = 0; j < 16; ++j) {
                float gate = 0.f;
#pragma unroll
                for (int q = 0; q < 16; ++q) {
                    int rb = __builtin_amdgcn_readlane(
                        __float_as_int(rv[j]), q);
                    gate = fmaf(__int_as_float(rb), wreg[q], gate);
                }
                const int nd = __builtin_amdgcn_readlane(ndv, j0 + j);
                if (s0 + j0 + j < n_edge) {  // wave-uniform guard
                    if (nd != cur) {
                        if (cur >= 0)
                            atomicAdd(&h[(size_t)cur * EDGE_DIM + lane], acc);
                        cur = nd;
                        acc = 0.f;
                    }
                    acc = fmaf(gate, xv[j], acc);
                }
            }
        }
        if (cur >= 0) atomicAdd(&h[(size_t)cur * EDGE_DIM + lane], acc);
    }
}

// ---------------------------------------------------------------------------
// Pack all 4 weight matrices into MFMA-fragment bf16 hi/lo order.
// ---------------------------------------------------------------------------
__device__ __forceinline__ void pack_body(const float* __restrict__ W,
                                          short* __restrict__ out, int t) {
    int l = t & 63, f = t >> 6;
    int kt = f >> 4, nt = f & 15;
    int kbase = kt * 32 + (l >> 4) * 8;
    int col = nt * 16 + (l & 15);
#pragma unroll
    for (int j = 0; j < 8; ++j) {
        float v = W[(kbase + j) * UPD + col];
        short hb = f2bf(v);
        short lb = f2bf(v - bf2f(hb));
        out[f * 1024 + l * 8 + j] = hb;
        out[f * 1024 + 512 + l * 8 + j] = lb;
    }
}

__global__ __launch_bounds__(256) void pack_all_kernel(
    const float* __restrict__ Wup, const float* __restrict__ W1,
    const float* __restrict__ W2, const float* __restrict__ W3,
    short* __restrict__ oup, short* __restrict__ o1, short* __restrict__ o2,
    short* __restrict__ o3) {
    const int b = blockIdx.x;
    if (b < 8) {
        pack_body(Wup, oup, b * 256 + threadIdx.x);
    } else if (b < 40) {
        pack_body(W1, o1, (b - 8) * 256 + threadIdx.x);
    } else if (b < 72) {
        pack_body(W2, o2, (b - 40) * 256 + threadIdx.x);
    } else {
        pack_body(W3, o3, (b - 72) * 256 + threadIdx.x);
    }
}

// ---------------------------------------------------------------------------
// MFMA node MLP, 128-node tile: 512 threads = 8 waves in 2(row-half) x
// 4(col-quarter). Per-wave work identical to the 64-node version (64 rows x
// 64 cols, 4x4 acc), but HALF the blocks -> half the B L2 traffic and half
// the per-node barrier count. LDS 130KB -> 1 block/CU (2 waves/SIMD, same
// as before).
// ---------------------------------------------------------------------------
template <int NK>
__device__ __forceinline__ void mm_layer(const short* AH, const short* AL,
                                         const short* __restrict__ Wpk,
                                         int lr, int lh, int lane, int wrow,
                                         int wcol, f32x4 acc[4][4]) {
    bf16x8 bc[4][2];
#pragma unroll
    for (int nf = 0; nf < 4; ++nf) {
        const short* p = Wpk + (wcol * 4 + nf) * 1024 + lane * 8;
        bc[nf][0] = *(const bf16x8*)(p);
        bc[nf][1] = *(const bf16x8*)(p + 512);
    }
#pragma unroll
    for (int kt = 0; kt < NK; ++kt) {
        bf16x8 a[4][2];
#pragma unroll
        for (int m = 0; m < 4; ++m) {
            int r = wrow * 64 + m * 16 + lr;
            int ch = (kt * 4 + lh) ^ (r & 7);
            int off = r * 256 + ch * 8;  // shorts
            a[m][0] = *(const bf16x8*)(AH + off);
            a[m][1] = *(const bf16x8*)(AL + off);
        }
        bf16x8 bn[4][2];
        if (kt + 1 < NK) {
#pragma unroll
            for (int nf = 0; nf < 4; ++nf) {
                const short* p =
                    Wpk + ((kt + 1) * 16 + wcol * 4 + nf) * 1024 + lane * 8;
                bn[nf][0] = *(const bf16x8*)(p);
                bn[nf][1] = *(const bf16x8*)(p + 512);
            }
        }
#pragma unroll
        for (int m = 0; m < 4; ++m)
#pragma unroll
            for (int nf = 0; nf < 4; ++nf)
                acc[m][nf] = __builtin_amdgcn_mfma_f32_16x16x32_bf16(
                    a[m][0], bc[nf][0], acc[m][nf], 0, 0, 0);
#pragma unroll
        for (int m = 0; m < 4; ++m)
#pragma unroll
            for (int nf = 0; nf < 4; ++nf)
                acc[m][nf] = __builtin_amdgcn_mfma_f32_16x16x32_bf16(
                    a[m][0], bc[nf][1], acc[m][nf], 0, 0, 0);
#pragma unroll
        for (int m = 0; m < 4; ++m)
#pragma unroll
            for (int nf = 0; nf < 4; ++nf)
                acc[m][nf] = __builtin_amdgcn_mfma_f32_16x16x32_bf16(
                    a[m][1], bc[nf][0], acc[m][nf], 0, 0, 0);
        if (kt + 1 < NK) {
#pragma unroll
            for (int nf = 0; nf < 4; ++nf) {
                bc[nf][0] = bn[nf][0];
                bc[nf][1] = bn[nf][1];
            }
        }
    }
}

template <bool ACT>
__device__ __forceinline__ void epilogue_store(f32x4 acc[4][4], short* AH,
                                               short* AL,
                                               const float* __restrict__ bias,
                                               int lr, int lh, int wrow,
                                               int wcol) {
    float bv[4] = {0.f, 0.f, 0.f, 0.f};
    if (bias) {
#pragma unroll
        for (int nf = 0; nf < 4; ++nf)
            bv[nf] = bias[wcol * 64 + nf * 16 + lr];
    }
#pragma unroll
    for (int m = 0; m < 4; ++m)
#pragma unroll
        for (int nf = 0; nf < 4; ++nf) {
            int c = wcol * 64 + nf * 16 + lr;
#pragma unroll
            for (int reg = 0; reg < 4; ++reg) {
                float v = acc[m][nf][reg] + bv[nf];
                if (ACT) {
                    float e = __expf(-v);
                    v = v * __builtin_amdgcn_rcpf(1.f + e);
                }
                int r = wrow * 64 + m * 16 + lh * 4 + reg;
                short hb, lb;
                split_trunc(v, hb, lb);
                int off = r * 256 + (((c >> 3) ^ (r & 7)) * 8) + (c & 7);
                AH[off] = hb;
                AL[off] = lb;
            }
        }
}

__global__ __launch_bounds__(512, 1) void node_mlp_mfma(
    const float* __restrict__ h,
    const short* __restrict__ Wup_pk, const short* __restrict__ W1_pk,
    const short* __restrict__ W2_pk, const short* __restrict__ W3_pk,
    const float* __restrict__ b1, const float* __restrict__ b2,
    const float* __restrict__ b3, const float* __restrict__ W_out,
    float* __restrict__ out, int nn) {
    __shared__ short AH[128 * 256];
    __shared__ short AL[128 * 256];
    __shared__ float Bpart[128 * 4];

    const int tid = threadIdx.x;
    const int lane = tid & 63;
    const int w = tid >> 6;          // 0..7
    const int wrow = w >> 2;         // 0..1
    const int wcol = w & 3;          // 0..3
    const int lr = lane & 15, lh = lane >> 4;
    const int node0 = blockIdx.x * 128;

    // Stage h tile (128 x 64 f32) -> hi/lo bf16, swizzled. 2048 float4 / 512.
#pragma unroll
    for (int i = 0; i < 4; ++i) {
        int idx4 = tid + i * 512;
        int r = idx4 >> 4, c4 = idx4 & 15;
        float4 v = {0.f, 0.f, 0.f, 0.f};
        if (node0 + r < nn)
            v = *(const float4*)(h + (size_t)(node0 + r) * EDGE_DIM + c4 * 4);
        short h0, h1, h2, h3, l0, l1, l2, l3;
        split_trunc(v.x, h0, l0);
        split_trunc(v.y, h1, l1);
        split_trunc(v.z, h2, l2);
        split_trunc(v.w, h3, l3);
        int off = r * 256 + (((c4 >> 1) ^ (r & 7)) * 8) + (c4 & 1) * 4;
        uint2 hw, lw;
        hw.x = (unsigned short)h0 | ((unsigned)(unsigned short)h1 << 16);
        hw.y = (unsigned short)h2 | ((unsigned)(unsigned short)h3 << 16);
        lw.x = (unsigned short)l0 | ((unsigned)(unsigned short)l1 << 16);
        lw.y = (unsigned short)l2 | ((unsigned)(unsigned short)l3 << 16);
        *(uint2*)(AH + off) = hw;
        *(uint2*)(AL + off) = lw;
    }
    __syncthreads();

    f32x4 acc[4][4];

#pragma unroll
    for (int m = 0; m < 4; ++m)
#pragma unroll
        for (int n = 0; n < 4; ++n) acc[m][n] = (f32x4){0.f, 0.f, 0.f, 0.f};
    mm_layer<2>(AH, AL, Wup_pk, lr, lh, lane, wrow, wcol, acc);
    __syncthreads();
    epilogue_store<false>(acc, AH, AL, nullptr, lr, lh, wrow, wcol);
    __syncthreads();

#pragma unroll
    for (int m = 0; m < 4; ++m)
#pragma unroll
        for (int n = 0; n < 4; ++n) acc[m][n] = (f32x4){0.f, 0.f, 0.f, 0.f};
    mm_layer<8>(AH, AL, W1_pk, lr, lh, lane, wrow, wcol, acc);
    __syncthreads();
    epilogue_store<true>(acc, AH, AL, b1, lr, lh, wrow, wcol);
    __syncthreads();

#pragma unroll
    for (int m = 0; m < 4; ++m)
#pragma unroll
        for (int n = 0; n < 4; ++n) acc[m][n] = (f32x4){0.f, 0.f, 0.f, 0.f};
    mm_layer<8>(AH, AL, W2_pk, lr, lh, lane, wrow, wcol, acc);
    __syncthreads();
    epilogue_store<true>(acc, AH, AL, b2, lr, lh, wrow, wcol);
    __syncthreads();

#pragma unroll
    for (int m = 0; m < 4; ++m)
#pragma unroll
        for (int n = 0; n < 4; ++n) acc[m][n] = (f32x4){0.f, 0.f, 0.f, 0.f};
    mm_layer<8>(AH, AL, W3_pk, lr, lh, lane, wrow, wcol, acc);

    float b3v[4], wo[4];
#pragma unroll
    for (int nf = 0; nf < 4; ++nf) {
        int c = wcol * 64 + nf * 16 + lr;
        b3v[nf] = b3[c];
        wo[nf] = W_out[c];
    }
#pragma unroll
    for (int m = 0; m < 4; ++m) {
#pragma unroll
        for (int reg = 0; reg < 4; ++reg) {
            float s = 0.f;
#pragma unroll
            for (int nf = 0; nf < 4; ++nf) {
                float v = acc[m][nf][reg] + b3v[nf];
                float e = __expf(-v);
                v = v * __builtin_amdgcn_rcpf(1.f + e);
                s = fmaf(v, wo[nf], s);
            }
            s += __shfl_xor(s, 1);
            s += __shfl_xor(s, 2);
            s += __shfl_xor(s, 4);
            s += __shfl_xor(s, 8);
            if (lr == 0) {
                int r = wrow * 64 + m * 16 + lh * 4 + reg;
                Bpart[r * 4 + wcol] = s;
            }
        }
    }
    __syncthreads();
    if (tid < 128) {
        float s = Bpart[tid * 4] + Bpart[tid * 4 + 1] + Bpart[tid * 4 + 2] +
                  Bpart[tid * 4 + 3];
        if (node0 + tid < nn) out[node0 + tid] = s;
    }
}

// ---------------------------------------------------------------------------
extern "C" void kernel_launch(void* const* d_in, const int* in_sizes, int n_in,
                              void* d_out, int out_size, void* d_ws, size_t ws_size,
                              hipStream_t stream) {
    const float* x     = (const float*)d_in[0];
    const float* rbf   = (const float*)d_in[1];
    const void*  idx   = d_in[2];
    const float* W_rbf = (const float*)d_in[4];
    const float* W_up  = (const float*)d_in[5];
    const float* W1    = (const float*)d_in[6];
    const float* b1    = (const float*)d_in[7];
    const float* W2    = (const float*)d_in[8];
    const float* b2    = (const float*)d_in[9];
    const float* W3    = (const float*)d_in[10];
    const float* b3    = (const float*)d_in[11];
    const float* W_out = (const float*)d_in[12];
    float* out = (float*)d_out;

    const int n_edge = in_sizes[0] / EDGE_DIM;
    const int nn = out_size;

    // Workspace layout (16B-aligned chunks)
    char* p = (char*)d_ws;
    float* h = (float*)p;            p += (size_t)nn * EDGE_DIM * sizeof(float);
    short* wup_pk = (short*)p;       p += 32 * 1024 * sizeof(short);
    short* w1_pk = (short*)p;        p += 128 * 1024 * sizeof(short);
    short* w2_pk = (short*)p;        p += 128 * 1024 * sizeof(short);
    short* w3_pk = (short*)p;        p += 128 * 1024 * sizeof(short);
    int* count = (int*)p;            p += (size_t)nn * sizeof(int);
    int* base = (int*)p;             p += (size_t)(nn + 1) * sizeof(int) + 12;
    int* cursor = (int*)p;           p += (size_t)nn * sizeof(int);
    int* partial = (int*)p;          p += 1024;
    int2* ordnode = (int2*)p;

    const int nblk_scan = (nn + 1023) / 1024;

    zero_ws_kernel<<<2048, 256, 0, stream>>>(
        (float4*)h, (long long)nn * EDGE_DIM / 4, count, nn);
    pack_all_kernel<<<104, 256, 0, stream>>>(W_up, W1, W2, W3, wup_pk, w1_pk,
                                             w2_pk, w3_pk);
    count_kernel<<<2048, 256, 0, stream>>>(idx, n_edge, nn, count);
    scan_a<<<nblk_scan, 256, 0, stream>>>(count, base, partial, nn);
    scan_b<<<1, 256, 0, stream>>>(partial, nblk_scan);
    scan_c<<<nblk_scan, 256, 0, stream>>>(base, cursor, partial, nn, n_edge);
    fill_order_kernel<<<2048, 256, 0, stream>>>(idx, n_edge, nn, cursor,
                                                ordnode);
    const int nchunks = (n_edge + 63) / 64;
    const int nblk_seg = (nchunks + 3) / 4;
    segsum2_kernel<<<nblk_seg, 256, 0, stream>>>(x, rbf, ordnode, W_rbf, h,
                                                 n_edge);

    const int nb = (nn + 127) / 128;
    node_mlp_mfma<<<nb, 512, 0, stream>>>(h, wup_pk, w1_pk, w2_pk, w3_pk,
                                          b1, b2, b3, W_out, out, nn);
}

// Round 16
// 307.377 us; speedup vs baseline: 1.2177x; 1.2177x over previous
//
#include <hip/hip_runtime.h>
#include <hip/hip_bf16.h>

#define EDGE_DIM 64
#define UPD 256

typedef __attribute__((ext_vector_type(8))) short bf16x8;
typedef __attribute__((ext_vector_type(4))) float f32x4;

__device__ __forceinline__ short f2bf(float v) {
    __hip_bfloat16 b = __float2bfloat16(v);
    return *(short*)&b;
}
__device__ __forceinline__ float bf2f(short s) {
    __hip_bfloat16 b = *(__hip_bfloat16*)&s;
    return __bfloat162float(b);
}

// Truncation hi/lo split (cheap, ~5 VALU ops).
__device__ __forceinline__ void split_trunc(float v, short& hi, short& lo) {
    unsigned u = __float_as_uint(v);
    unsigned hu = u & 0xFFFF0000u;
    hi = (short)(hu >> 16);
    float rem = v - __uint_as_float(hu);
    lo = (short)(__float_as_uint(rem) >> 16);
}

// ---------------------------------------------------------------------------
// Workspace zeroing: h (float4-wide) + count, one launch.
// ---------------------------------------------------------------------------
__global__ __launch_bounds__(256) void zero_ws_kernel(
    float4* __restrict__ h4, long long n4, int* __restrict__ count, int nn) {
    const long long t = (long long)blockIdx.x * blockDim.x + threadIdx.x;
    const long long stride = (long long)gridDim.x * blockDim.x;
    const float4 z = {0.f, 0.f, 0.f, 0.f};
    for (long long i = t; i < n4; i += stride) h4[i] = z;
    for (long long i = t; i < nn; i += stride) count[i] = 0;
}

// ---------------------------------------------------------------------------
// Per-block idx-dtype detection (deterministic across blocks).
// ---------------------------------------------------------------------------
__device__ __forceinline__ int detect_use64_block(const void* idx_v,
                                                  int n_edge, int nn,
                                                  int* bad_s) {
    if (threadIdx.x == 0) *bad_s = 0;
    __syncthreads();
    const long long* p = (const long long*)idx_v;
    int i = threadIdx.x;
    if (i < 256 && i < n_edge) {
        long long v = p[i];
        if (v < 0 || v >= (long long)nn) *bad_s = 1;  // benign race
    }
    __syncthreads();
    return !(*bad_s);
}

// ---------------------------------------------------------------------------
// Counting sort phase A: per-node histogram + per-edge rank (slotofs).
// The atomicAdd return value IS the edge's within-node rank: recording it
// makes the later fill pass atomic-free.
// ---------------------------------------------------------------------------
__global__ __launch_bounds__(256) void count_kernel(
    const void* __restrict__ idx_v, int n_edge, int nn,
    int* __restrict__ count, int* __restrict__ slotofs) {
    __shared__ int bad_s;
    const int use64 = detect_use64_block(idx_v, n_edge, nn, &bad_s);
    const long long* i64 = (const long long*)idx_v;
    const int* i32 = (const int*)idx_v;
    for (int e = blockIdx.x * blockDim.x + threadIdx.x; e < n_edge;
         e += gridDim.x * blockDim.x) {
        int n = use64 ? (int)i64[e] : i32[e];
        slotofs[e] = atomicAdd(&count[n], 1);
    }
}

// ---------------------------------------------------------------------------
// Exclusive scan over count[nn] -> base[nn+1]  (3 kernels).
// ---------------------------------------------------------------------------
__global__ __launch_bounds__(256) void scan_a(const int* __restrict__ count,
                                              int* __restrict__ base,
                                              int* __restrict__ partial,
                                              int nn) {
    __shared__ int s[256];
    const int tid = threadIdx.x;
    const int i0 = blockIdx.x * 1024 + tid * 4;
    int c[4], tsum = 0;
#pragma unroll
    for (int j = 0; j < 4; ++j) {
        c[j] = (i0 + j < nn) ? count[i0 + j] : 0;
        tsum += c[j];
    }
    s[tid] = tsum;
    __syncthreads();
    for (int off = 1; off < 256; off <<= 1) {
        int v = (tid >= off) ? s[tid - off] : 0;
        __syncthreads();
        s[tid] += v;
        __syncthreads();
    }
    int run = s[tid] - tsum;
    if (tid == 255) partial[blockIdx.x] = s[255];
#pragma unroll
    for (int j = 0; j < 4; ++j) {
        if (i0 + j < nn) base[i0 + j] = run;
        run += c[j];
    }
}

__global__ __launch_bounds__(256) void scan_b(int* __restrict__ partial,
                                              int nblk) {
    __shared__ int s[256];
    const int tid = threadIdx.x;
    int v = (tid < nblk) ? partial[tid] : 0;
    s[tid] = v;
    __syncthreads();
    for (int off = 1; off < 256; off <<= 1) {
        int u = (tid >= off) ? s[tid - off] : 0;
        __syncthreads();
        s[tid] += u;
        __syncthreads();
    }
    if (tid < nblk) partial[tid] = s[tid] - v;
}

__global__ __launch_bounds__(256) void scan_c(int* __restrict__ base,
                                              const int* __restrict__ partial,
                                              int nn, int n_edge) {
    const int tid = threadIdx.x;
    const int b = blockIdx.x;
    const int add = partial[b];
    const int i0 = b * 1024 + tid * 4;
#pragma unroll
    for (int j = 0; j < 4; ++j) {
        int i = i0 + j;
        if (i < nn) base[i] += add;
    }
    if (b == 0 && tid == 0) base[nn] = n_edge;
}

// ---------------------------------------------------------------------------
// Phase B: ATOMIC-FREE scatter of edge/node ids into sorted slot order.
// slot = base[n] + slotofs[e]; base is L2-resident (400KB).
// ---------------------------------------------------------------------------
__global__ __launch_bounds__(256) void fill_order_kernel(
    const void* __restrict__ idx_v, int n_edge, int nn,
    const int* __restrict__ base, const int* __restrict__ slotofs,
    int* __restrict__ order, int* __restrict__ nodeof) {
    __shared__ int bad_s;
    const int use64 = detect_use64_block(idx_v, n_edge, nn, &bad_s);
    const long long* i64 = (const long long*)idx_v;
    const int* i32 = (const int*)idx_v;
    for (int e = blockIdx.x * blockDim.x + threadIdx.x; e < n_edge;
         e += gridDim.x * blockDim.x) {
        int n = use64 ? (int)i64[e] : i32[e];
        int p = base[n] + slotofs[e];
        order[p] = e;
        nodeof[p] = n;
    }
}

// ---------------------------------------------------------------------------
// Phase C: all-vector-path segmented sum (R12/R13 lean form, 28 VGPR).
// ---------------------------------------------------------------------------
__global__ __launch_bounds__(256) void segsum2_kernel(
    const float* __restrict__ x, const float* __restrict__ rbf,
    const int* __restrict__ order, const int* __restrict__ nodeof,
    const float* __restrict__ Wrbf, float* __restrict__ h, int n_edge) {
    const int lane = threadIdx.x & 63;
    float wreg[16];
#pragma unroll
    for (int q = 0; q < 16; ++q) wreg[q] = Wrbf[q * EDGE_DIM + lane];

    const int wid = threadIdx.x >> 6;
    const int nchunks = (n_edge + 63) >> 6;
    const int stride = gridDim.x * 4;

    for (int c = blockIdx.x * 4 + wid; c < nchunks; c += stride) {
        const int s0 = c * 64;
        int slot = s0 + lane;
        if (slot >= n_edge) slot = n_edge - 1;  // clamp (tail only)
        const int ev = order[slot];             // per-lane vector load
        const int ndv = nodeof[slot];           // per-lane vector load

        float acc = 0.f;
        int cur = -1;
#pragma unroll
        for (int g = 0; g < 4; ++g) {
            const int j0 = g * 16;
            int e[16];
            float xv[16], rv[16];
#pragma unroll
            for (int j = 0; j < 16; ++j) {
                e[j] = __builtin_amdgcn_readlane(ev, j0 + j);  // SGPR
                xv[j] = x[(size_t)e[j] * EDGE_DIM + lane];
                rv[j] = rbf[(size_t)e[j] * 16 + (lane & 15)];
            }
#pragma unroll
            for (int j = 0; j < 16; ++j) {
                float gate = 0.f;
#pragma unroll
                for (int q = 0; q < 16; ++q) {
                    int rb = __builtin_amdgcn_readlane(
                        __float_as_int(rv[j]), q);
                    gate = fmaf(__int_as_float(rb), wreg[q], gate);
                }
                const int nd = __builtin_amdgcn_readlane(ndv, j0 + j);
                if (s0 + j0 + j < n_edge) {  // wave-uniform guard
                    if (nd != cur) {
                        if (cur >= 0)
                            atomicAdd(&h[(size_t)cur * EDGE_DIM + lane], acc);
                        cur = nd;
                        acc = 0.f;
                    }
                    acc = fmaf(gate, xv[j], acc);
                }
            }
        }
        if (cur >= 0) atomicAdd(&h[(size_t)cur * EDGE_DIM + lane], acc);
    }
}

// ---------------------------------------------------------------------------
// Pack all 4 weight matrices into MFMA-fragment bf16 hi/lo order.
// ---------------------------------------------------------------------------
__device__ __forceinline__ void pack_body(const float* __restrict__ W,
                                          short* __restrict__ out, int t) {
    int l = t & 63, f = t >> 6;
    int kt = f >> 4, nt = f & 15;
    int kbase = kt * 32 + (l >> 4) * 8;
    int col = nt * 16 + (l & 15);
#pragma unroll
    for (int j = 0; j < 8; ++j) {
        float v = W[(kbase + j) * UPD + col];
        short hb = f2bf(v);
        short lb = f2bf(v - bf2f(hb));
        out[f * 1024 + l * 8 + j] = hb;
        out[f * 1024 + 512 + l * 8 + j] = lb;
    }
}

__global__ __launch_bounds__(256) void pack_all_kernel(
    const float* __restrict__ Wup, const float* __restrict__ W1,
    const float* __restrict__ W2, const float* __restrict__ W3,
    short* __restrict__ oup, short* __restrict__ o1, short* __restrict__ o2,
    short* __restrict__ o3) {
    const int b = blockIdx.x;
    if (b < 8) {
        pack_body(Wup, oup, b * 256 + threadIdx.x);
    } else if (b < 40) {
        pack_body(W1, o1, (b - 8) * 256 + threadIdx.x);
    } else if (b < 72) {
        pack_body(W2, o2, (b - 40) * 256 + threadIdx.x);
    } else {
        pack_body(W3, o3, (b - 72) * 256 + threadIdx.x);
    }
}

// ---------------------------------------------------------------------------
// MFMA node MLP (R11/R13 proven form: 64-node tile, 4 waves, 2 blocks/CU,
// B-prefetch, trunc split, cheap SiLU).
// ---------------------------------------------------------------------------
template <int NK>
__device__ __forceinline__ void mm_layer(const short* AH, const short* AL,
                                         const short* __restrict__ Wpk,
                                         int lr, int lh, int lane, int wq,
                                         f32x4 acc[4][4]) {
    bf16x8 bc[4][2];
#pragma unroll
    for (int nf = 0; nf < 4; ++nf) {
        const short* p = Wpk + (wq * 4 + nf) * 1024 + lane * 8;
        bc[nf][0] = *(const bf16x8*)(p);
        bc[nf][1] = *(const bf16x8*)(p + 512);
    }
#pragma unroll
    for (int kt = 0; kt < NK; ++kt) {
        bf16x8 a[4][2];
#pragma unroll
        for (int m = 0; m < 4; ++m) {
            int r = m * 16 + lr;
            int ch = (kt * 4 + lh) ^ (r & 7);
            int off = r * 256 + ch * 8;  // shorts
            a[m][0] = *(const bf16x8*)(AH + off);
            a[m][1] = *(const bf16x8*)(AL + off);
        }
        bf16x8 bn[4][2];
        if (kt + 1 < NK) {
#pragma unroll
            for (int nf = 0; nf < 4; ++nf) {
                const short* p =
                    Wpk + ((kt + 1) * 16 + wq * 4 + nf) * 1024 + lane * 8;
                bn[nf][0] = *(const bf16x8*)(p);
                bn[nf][1] = *(const bf16x8*)(p + 512);
            }
        }
#pragma unroll
        for (int m = 0; m < 4; ++m)
#pragma unroll
            for (int nf = 0; nf < 4; ++nf)
                acc[m][nf] = __builtin_amdgcn_mfma_f32_16x16x32_bf16(
                    a[m][0], bc[nf][0], acc[m][nf], 0, 0, 0);
#pragma unroll
        for (int m = 0; m < 4; ++m)
#pragma unroll
            for (int nf = 0; nf < 4; ++nf)
                acc[m][nf] = __builtin_amdgcn_mfma_f32_16x16x32_bf16(
                    a[m][0], bc[nf][1], acc[m][nf], 0, 0, 0);
#pragma unroll
        for (int m = 0; m < 4; ++m)
#pragma unroll
            for (int nf = 0; nf < 4; ++nf)
                acc[m][nf] = __builtin_amdgcn_mfma_f32_16x16x32_bf16(
                    a[m][1], bc[nf][0], acc[m][nf], 0, 0, 0);
        if (kt + 1 < NK) {
#pragma unroll
            for (int nf = 0; nf < 4; ++nf) {
                bc[nf][0] = bn[nf][0];
                bc[nf][1] = bn[nf][1];
            }
        }
    }
}

template <bool ACT>
__device__ __forceinline__ void epilogue_store(f32x4 acc[4][4], short* AH,
                                               short* AL,
                                               const float* __restrict__ bias,
                                               int lr, int lh, int wq) {
    float bv[4] = {0.f, 0.f, 0.f, 0.f};
    if (bias) {
#pragma unroll
        for (int nf = 0; nf < 4; ++nf) bv[nf] = bias[wq * 64 + nf * 16 + lr];
    }
#pragma unroll
    for (int m = 0; m < 4; ++m)
#pragma unroll
        for (int nf = 0; nf < 4; ++nf) {
            int c = wq * 64 + nf * 16 + lr;
#pragma unroll
            for (int reg = 0; reg < 4; ++reg) {
                float v = acc[m][nf][reg] + bv[nf];
                if (ACT) {
                    float e = __expf(-v);
                    v = v * __builtin_amdgcn_rcpf(1.f + e);
                }
                int r = m * 16 + lh * 4 + reg;
                short hb, lb;
                split_trunc(v, hb, lb);
                int off = r * 256 + (((c >> 3) ^ (r & 7)) * 8) + (c & 7);
                AH[off] = hb;
                AL[off] = lb;
            }
        }
}

__global__ __launch_bounds__(256, 2) void node_mlp_mfma(
    const float* __restrict__ h,
    const short* __restrict__ Wup_pk, const short* __restrict__ W1_pk,
    const short* __restrict__ W2_pk, const short* __restrict__ W3_pk,
    const float* __restrict__ b1, const float* __restrict__ b2,
    const float* __restrict__ b3, const float* __restrict__ W_out,
    float* __restrict__ out, int nn) {
    __shared__ short AH[64 * 256];
    __shared__ short AL[64 * 256];
    __shared__ float Bpart[64 * 4];

    const int tid = threadIdx.x;
    const int lane = tid & 63, wq = tid >> 6;
    const int lr = lane & 15, lh = lane >> 4;
    const int node0 = blockIdx.x * 64;

#pragma unroll
    for (int i = 0; i < 4; ++i) {
        int idx4 = tid + i * 256;
        int r = idx4 >> 4, c4 = idx4 & 15;
        float4 v = {0.f, 0.f, 0.f, 0.f};
        if (node0 + r < nn)
            v = *(const float4*)(h + (size_t)(node0 + r) * EDGE_DIM + c4 * 4);
        short h0, h1, h2, h3, l0, l1, l2, l3;
        split_trunc(v.x, h0, l0);
        split_trunc(v.y, h1, l1);
        split_trunc(v.z, h2, l2);
        split_trunc(v.w, h3, l3);
        int off = r * 256 + (((c4 >> 1) ^ (r & 7)) * 8) + (c4 & 1) * 4;
        uint2 hw, lw;
        hw.x = (unsigned short)h0 | ((unsigned)(unsigned short)h1 << 16);
        hw.y = (unsigned short)h2 | ((unsigned)(unsigned short)h3 << 16);
        lw.x = (unsigned short)l0 | ((unsigned)(unsigned short)l1 << 16);
        lw.y = (unsigned short)l2 | ((unsigned)(unsigned short)l3 << 16);
        *(uint2*)(AH + off) = hw;
        *(uint2*)(AL + off) = lw;
    }
    __syncthreads();

    f32x4 acc[4][4];

#pragma unroll
    for (int m = 0; m < 4; ++m)
#pragma unroll
        for (int n = 0; n < 4; ++n) acc[m][n] = (f32x4){0.f, 0.f, 0.f, 0.f};
    mm_layer<2>(AH, AL, Wup_pk, lr, lh, lane, wq, acc);
    __syncthreads();
    epilogue_store<false>(acc, AH, AL, nullptr, lr, lh, wq);
    __syncthreads();

#pragma unroll
    for (int m = 0; m < 4; ++m)
#pragma unroll
        for (int n = 0; n < 4; ++n) acc[m][n] = (f32x4){0.f, 0.f, 0.f, 0.f};
    mm_layer<8>(AH, AL, W1_pk, lr, lh, lane, wq, acc);
    __syncthreads();
    epilogue_store<true>(acc, AH, AL, b1, lr, lh, wq);
    __syncthreads();

#pragma unroll
    for (int m = 0; m < 4; ++m)
#pragma unroll
        for (int n = 0; n < 4; ++n) acc[m][n] = (f32x4){0.f, 0.f, 0.f, 0.f};
    mm_layer<8>(AH, AL, W2_pk, lr, lh, lane, wq, acc);
    __syncthreads();
    epilogue_store<true>(acc, AH, AL, b2, lr, lh, wq);
    __syncthreads();

#pragma unroll
    for (int m = 0; m < 4; ++m)
#pragma unroll
        for (int n = 0; n < 4; ++n) acc[m][n] = (f32x4){0.f, 0.f, 0.f, 0.f};
    mm_layer<8>(AH, AL, W3_pk, lr, lh, lane, wq, acc);

    float b3v[4], wo[4];
#pragma unroll
    for (int nf = 0; nf < 4; ++nf) {
        int c = wq * 64 + nf * 16 + lr;
        b3v[nf] = b3[c];
        wo[nf] = W_out[c];
    }
#pragma unroll
    for (int m = 0; m < 4; ++m) {
#pragma unroll
        for (int reg = 0; reg < 4; ++reg) {
            float s = 0.f;
#pragma unroll
            for (int nf = 0; nf < 4; ++nf) {
                float v = acc[m][nf][reg] + b3v[nf];
                float e = __expf(-v);
                v = v * __builtin_amdgcn_rcpf(1.f + e);
                s = fmaf(v, wo[nf], s);
            }
            s += __shfl_xor(s, 1);
            s += __shfl_xor(s, 2);
            s += __shfl_xor(s, 4);
            s += __shfl_xor(s, 8);
            if (lr == 0) Bpart[(m * 16 + lh * 4 + reg) * 4 + wq] = s;
        }
    }
    __syncthreads();
    if (tid < 64) {
        float s = Bpart[tid * 4] + Bpart[tid * 4 + 1] + Bpart[tid * 4 + 2] +
                  Bpart[tid * 4 + 3];
        if (node0 + tid < nn) out[node0 + tid] = s;
    }
}

// ---------------------------------------------------------------------------
extern "C" void kernel_launch(void* const* d_in, const int* in_sizes, int n_in,
                              void* d_out, int out_size, void* d_ws, size_t ws_size,
                              hipStream_t stream) {
    const float* x     = (const float*)d_in[0];
    const float* rbf   = (const float*)d_in[1];
    const void*  idx   = d_in[2];
    const float* W_rbf = (const float*)d_in[4];
    const float* W_up  = (const float*)d_in[5];
    const float* W1    = (const float*)d_in[6];
    const float* b1    = (const float*)d_in[7];
    const float* W2    = (const float*)d_in[8];
    const float* b2    = (const float*)d_in[9];
    const float* W3    = (const float*)d_in[10];
    const float* b3    = (const float*)d_in[11];
    const float* W_out = (const float*)d_in[12];
    float* out = (float*)d_out;

    const int n_edge = in_sizes[0] / EDGE_DIM;
    const int nn = out_size;

    // Workspace layout
    char* p = (char*)d_ws;
    float* h = (float*)p;            p += (size_t)nn * EDGE_DIM * sizeof(float);
    short* wup_pk = (short*)p;       p += 32 * 1024 * sizeof(short);
    short* w1_pk = (short*)p;        p += 128 * 1024 * sizeof(short);
    short* w2_pk = (short*)p;        p += 128 * 1024 * sizeof(short);
    short* w3_pk = (short*)p;        p += 128 * 1024 * sizeof(short);
    int* count = (int*)p;            p += (size_t)nn * sizeof(int);
    int* base = (int*)p;             p += (size_t)(nn + 1) * sizeof(int) + 12;
    int* partial = (int*)p;          p += 1024;
    int* slotofs = (int*)p;          p += (size_t)n_edge * sizeof(int);
    int* order = (int*)p;            p += (size_t)n_edge * sizeof(int);
    int* nodeof = (int*)p;

    const int nblk_scan = (nn + 1023) / 1024;

    zero_ws_kernel<<<2048, 256, 0, stream>>>(
        (float4*)h, (long long)nn * EDGE_DIM / 4, count, nn);
    pack_all_kernel<<<104, 256, 0, stream>>>(W_up, W1, W2, W3, wup_pk, w1_pk,
                                             w2_pk, w3_pk);
    count_kernel<<<2048, 256, 0, stream>>>(idx, n_edge, nn, count, slotofs);
    scan_a<<<nblk_scan, 256, 0, stream>>>(count, base, partial, nn);
    scan_b<<<1, 256, 0, stream>>>(partial, nblk_scan);
    scan_c<<<nblk_scan, 256, 0, stream>>>(base, partial, nn, n_edge);
    fill_order_kernel<<<2048, 256, 0, stream>>>(idx, n_edge, nn, base,
                                                slotofs, order, nodeof);
    const int nchunks = (n_edge + 63) / 64;
    const int nblk_seg = (nchunks + 3) / 4;
    segsum2_kernel<<<nblk_seg, 256, 0, stream>>>(x, rbf, order, nodeof,
                                                 W_rbf, h, n_edge);

    const int nb = (nn + 63) / 64;
    node_mlp_mfma<<<nb, 256, 0, stream>>>(h, wup_pk, w1_pk, w2_pk, w3_pk,
                                          b1, b2, b3, W_out, out, nn);
}